// Round 8
// baseline (803.659 us; speedup 1.0000x reference)
//
#include <hip/hip_runtime.h>

typedef float f32x4 __attribute__((ext_vector_type(4)));
typedef int   i32x4 __attribute__((ext_vector_type(4)));
typedef char  s8x16 __attribute__((ext_vector_type(16)));

#define GAS __attribute__((address_space(1)))
#define LAS __attribute__((address_space(3)))
#define SBAR __builtin_amdgcn_sched_barrier(0)

constexpr int M = 8192;       // B*S
constexpr int N = 16384;      // D_OUT
constexpr int K = 4096;       // D_IN
constexpr long long NX = (long long)M * K;   // 33,554,432
constexpr long long NW = (long long)N * K;   // 67,108,864
constexpr int NPART = 2048;
constexpr int NKT = 32;       // K / 128

// ---------------- reductions ----------------

__global__ void reduce_absmax_kernel(const float* __restrict__ x,
                                     unsigned* __restrict__ gmax, int n4) {
  float m = 0.f;
  int stride = gridDim.x * blockDim.x;
  for (int i = blockIdx.x * blockDim.x + threadIdx.x; i < n4; i += stride) {
    f32x4 v = *(const f32x4*)(x + (size_t)i * 4);
    m = fmaxf(m, fmaxf(fmaxf(fabsf(v[0]), fabsf(v[1])),
                       fmaxf(fabsf(v[2]), fabsf(v[3]))));
  }
#pragma unroll
  for (int off = 32; off > 0; off >>= 1) m = fmaxf(m, __shfl_down(m, off));
  __shared__ float sm[4];
  int lane = threadIdx.x & 63, wid = threadIdx.x >> 6;
  if (lane == 0) sm[wid] = m;
  __syncthreads();
  if (threadIdx.x == 0) {
    m = fmaxf(fmaxf(sm[0], sm[1]), fmaxf(sm[2], sm[3]));
    atomicMax(gmax, __float_as_uint(m));  // |x| >= 0: bit-order == float-order
  }
}

__global__ void reduce_abssum_kernel(const float* __restrict__ w,
                                     float* __restrict__ partials, int n4) {
  float s = 0.f;
  int stride = gridDim.x * blockDim.x;
  for (int i = blockIdx.x * blockDim.x + threadIdx.x; i < n4; i += stride) {
    f32x4 v = *(const f32x4*)(w + (size_t)i * 4);
    s += fabsf(v[0]) + fabsf(v[1]) + fabsf(v[2]) + fabsf(v[3]);
  }
#pragma unroll
  for (int off = 32; off > 0; off >>= 1) s += __shfl_down(s, off);
  __shared__ float sm[4];
  int lane = threadIdx.x & 63, wid = threadIdx.x >> 6;
  if (lane == 0) sm[wid] = s;
  __syncthreads();
  if (threadIdx.x == 0) partials[blockIdx.x] = (sm[0] + sm[1]) + (sm[2] + sm[3]);
}

__global__ void finalize_kernel(const unsigned* __restrict__ gbits,
                                const float* __restrict__ partials,
                                float* __restrict__ params) {
  __shared__ double sd[256];
  double s = 0.0;
  for (int i = threadIdx.x; i < NPART; i += 256) s += (double)partials[i];
  sd[threadIdx.x] = s;
  __syncthreads();
  for (int h = 128; h > 0; h >>= 1) {
    if (threadIdx.x < h) sd[threadIdx.x] += sd[threadIdx.x + h];
    __syncthreads();
  }
  if (threadIdx.x == 0) {
    float beta  = fmaxf((float)(sd[0] / (double)NW), 1e-5f);
    float gamma = fmaxf(__uint_as_float(gbits[0]), 1e-5f);
    params[0] = 128.0f / gamma;          // activation scale (q/gamma)
    params[1] = beta;                    // weight divisor
    params[2] = beta * gamma / 128.0f;   // output rescale
  }
}

// ---------------- quantization ----------------

__global__ void quant_x_kernel(const float* __restrict__ x,
                               char* __restrict__ xq,
                               const float* __restrict__ params, int n16) {
  float s = params[0];
  int stride = gridDim.x * blockDim.x;
  for (int i = blockIdx.x * blockDim.x + threadIdx.x; i < n16; i += stride) {
    const f32x4* p = (const f32x4*)(x + (size_t)i * 16);
    s8x16 o;
#pragma unroll
    for (int v = 0; v < 4; ++v) {
      f32x4 t = p[v];
#pragma unroll
      for (int k = 0; k < 4; ++k) {
        float r = fminf(fmaxf(rintf(t[k] * s), -128.f), 127.f);
        o[v * 4 + k] = (char)(int)r;
      }
    }
    *(s8x16*)(xq + (size_t)i * 16) = o;
  }
}

// B in MFMA-FRAGMENT layout: 16B chunk u  (u = (nr16*256 + kc)*16 + r16)
// holds W[nr16*16 + r16][kc*16 .. +16) quantized to {0,1}.
// GEMM lane (q4,r16) load for (nblk16, j, t, kh) is then one coalesced
// global_load_dwordx4 at ((nb16+j)*256 + t*8+kh*4+q4)*256 + r16*16.
__global__ void quant_w_kernel(const float* __restrict__ w,
                               char* __restrict__ wq2,
                               const float* __restrict__ params, int nchunks) {
  float beta = params[1];
  int stride = gridDim.x * blockDim.x;
  for (int u = blockIdx.x * blockDim.x + threadIdx.x; u < nchunks; u += stride) {
    const int nr16 = u >> 12;
    const int kc   = (u >> 4) & 255;
    const int r16  = u & 15;
    const float* src = w + (size_t)(nr16 * 16 + r16) * K + kc * 16;
    s8x16 o;
#pragma unroll
    for (int v = 0; v < 4; ++v) {
      f32x4 t = *(const f32x4*)(src + v * 4);
#pragma unroll
      for (int k = 0; k < 4; ++k)
        o[v * 4 + k] = (rintf(fabsf(t[k]) / beta) >= 1.0f) ? (char)1 : (char)0;
    }
    *(s8x16*)(wq2 + (size_t)u * 16) = o;
  }
}

// ---------------- GEMM: 256x256, 8 waves (2m x 4n), K-tile 128 ----------------
// A via LDS (3-ring, 32KB/slot, 1 barrier/tile, explicit vmcnt for the
// untrackable global_load_lds).  B DIRECT global->VGPR from fragment-ordered
// wq2 (compiler scoreboards these register loads), double-buffered bfE/bfO.
// LDS traffic/tile: A write 32KB + A read 128KB (~2048 cyc) < MFMA 2611 cyc
// -> matrix pipe binds (rounds 5-7: 256KB through LDS ~= MFMA, schedule-invariant
// ~590us).  Issue order sA before lB each tile + in-order vmcnt retirement
// means the compiler's own bf-waits also certify sA; explicit vmcnt kept.

__global__ __launch_bounds__(512) void gemm_kernel(
    const char* __restrict__ A,    // xq int8 [M][K] linear
    const char* __restrict__ Bq,   // wq2 fragment layout
    float* __restrict__ C,         // [M][N] fp32
    const float* __restrict__ params) {
  __shared__ __align__(16) char lds[98304];   // 3 x 32KB A ring

  const int tid  = threadIdx.x;
  const int lane = tid & 63, wid = tid >> 6;
  const int wm = wid >> 2, wn = wid & 3;      // 2x4 waves, each 128x64
  const int r16 = lane & 15, q4 = lane >> 4;

  // XCD mapping: XCD c owns m-tiles [c*4, c*4+4) x all 64 n-tiles, m fastest
  // (4 m-blocks share each B panel in L2 while it streams).
  const int wg = (blockIdx.x & 7) * 256 + (blockIdx.x >> 3);
  const int c  = wg >> 8, l = wg & 255;
  const int m0 = (c * 4 + (l & 3)) * 256;
  const int n0 = (l >> 2) * 256;

  // ---- A staging (proven round-7 mapping, A only) ----
  const int csw = ((lane & 7) ^ ((lane >> 3) & 7)) * 16;
  const char* gA = A + (size_t)(m0 + wid * 32 + (lane >> 3)) * K + csw;
  const int dA = wid * 4096 + lane * 16;

#define STAGE_A(T, SLOTOFF) do { \
    char* Lp = lds + (SLOTOFF); \
    const char* ap = gA + (size_t)(T) * 128; \
    __builtin_amdgcn_global_load_lds((const GAS void*)(ap),           (LAS void*)(Lp + dA),        16, 0, 0); \
    __builtin_amdgcn_global_load_lds((const GAS void*)(ap +  8 * K),  (LAS void*)(Lp + dA + 1024), 16, 0, 0); \
    __builtin_amdgcn_global_load_lds((const GAS void*)(ap + 16 * K),  (LAS void*)(Lp + dA + 2048), 16, 0, 0); \
    __builtin_amdgcn_global_load_lds((const GAS void*)(ap + 24 * K),  (LAS void*)(Lp + dA + 3072), 16, 0, 0); \
  } while (0)

  // ---- B direct loads: bB + j*65536 + t*2048 + kh*1024 ----
  const int nb16 = (n0 >> 4) + wn * 4;
  const char* bB = Bq + ((size_t)(nb16 * 256 + q4) * 16 + r16) * 16;

#define LOAD_B(T, BF) do { \
    const char* bp = bB + (size_t)(T) * 2048; \
    BF[0] = *(const i32x4*)(bp); \
    BF[1] = *(const i32x4*)(bp + 65536); \
    BF[2] = *(const i32x4*)(bp + 131072); \
    BF[3] = *(const i32x4*)(bp + 196608); \
    BF[4] = *(const i32x4*)(bp + 1024); \
    BF[5] = *(const i32x4*)(bp + 65536 + 1024); \
    BF[6] = *(const i32x4*)(bp + 131072 + 1024); \
    BF[7] = *(const i32x4*)(bp + 196608 + 1024); \
  } while (0)

  // ---- A fragment reads (swizzled, conflict-free; proven) ----
  const int abase = (wm * 128 + r16) * 128;
  const int sw0 = ((q4) ^ (r16 & 7)) * 16;
  const int sw1 = ((4 + q4) ^ (r16 & 7)) * 16;

  i32x4 acc[8][4] = {};

#define COMPUTE(BF, SLOTOFF) do { \
    const char* bufp = lds + (SLOTOFF); \
    i32x4 af[8]; \
    _Pragma("unroll") \
    for (int i = 0; i < 8; ++i) af[i] = *(const i32x4*)(bufp + abase + i * 2048 + sw0); \
    __builtin_amdgcn_s_setprio(1); \
    _Pragma("unroll") \
    for (int i = 0; i < 8; ++i) { \
      acc[i][0] = __builtin_amdgcn_mfma_i32_16x16x64_i8(af[i], BF[0], acc[i][0], 0, 0, 0); \
      acc[i][1] = __builtin_amdgcn_mfma_i32_16x16x64_i8(af[i], BF[1], acc[i][1], 0, 0, 0); \
      acc[i][2] = __builtin_amdgcn_mfma_i32_16x16x64_i8(af[i], BF[2], acc[i][2], 0, 0, 0); \
      acc[i][3] = __builtin_amdgcn_mfma_i32_16x16x64_i8(af[i], BF[3], acc[i][3], 0, 0, 0); \
    } \
    __builtin_amdgcn_s_setprio(0); \
    _Pragma("unroll") \
    for (int i = 0; i < 8; ++i) af[i] = *(const i32x4*)(bufp + abase + i * 2048 + sw1); \
    __builtin_amdgcn_s_setprio(1); \
    _Pragma("unroll") \
    for (int i = 0; i < 8; ++i) { \
      acc[i][0] = __builtin_amdgcn_mfma_i32_16x16x64_i8(af[i], BF[4], acc[i][0], 0, 0, 0); \
      acc[i][1] = __builtin_amdgcn_mfma_i32_16x16x64_i8(af[i], BF[5], acc[i][1], 0, 0, 0); \
      acc[i][2] = __builtin_amdgcn_mfma_i32_16x16x64_i8(af[i], BF[6], acc[i][2], 0, 0, 0); \
      acc[i][3] = __builtin_amdgcn_mfma_i32_16x16x64_i8(af[i], BF[7], acc[i][3], 0, 0, 0); \
    } \
    __builtin_amdgcn_s_setprio(0); \
  } while (0)

  i32x4 bfE[8], bfO[8];

  // prologue: A tiles 0,1 staged (slots 0,1), B tile 0 -> bfE
  STAGE_A(0, 0); SBAR;
  STAGE_A(1, 32768); SBAR;
  LOAD_B(0, bfE); SBAR;
  asm volatile("s_waitcnt vmcnt(12)" ::: "memory");   // certify sA(0); leaves sA(1)+lB(0)
  SBAR;

  int rc = 0;   // ring slot of tile t (byte offset /32768)
  for (int tt = 0; tt < 15; ++tt) {
    const int t = tt * 2;
    int rs = rc + 2; if (rs >= 3) rs -= 3;
    // ---- even tile t: consume bfE ----
    __builtin_amdgcn_s_barrier(); SBAR;
    STAGE_A(t + 2, rs * 32768); SBAR;    // sA issued BEFORE lB (vmcnt order)
    LOAD_B(t + 1, bfO); SBAR;
    COMPUTE(bfE, rc * 32768);
    SBAR;
    asm volatile("s_waitcnt vmcnt(12)" ::: "memory");  // certify sA(t+1)+lB(t)
    SBAR;
    rc = rc + 1; if (rc >= 3) rc -= 3;
    rs = rc + 2; if (rs >= 3) rs -= 3;
    // ---- odd tile t+1: consume bfO ----
    __builtin_amdgcn_s_barrier(); SBAR;
    STAGE_A(t + 3, rs * 32768); SBAR;
    LOAD_B(t + 2, bfE); SBAR;
    COMPUTE(bfO, rc * 32768);
    SBAR;
    asm volatile("s_waitcnt vmcnt(12)" ::: "memory");
    SBAR;
    rc = rc + 1; if (rc >= 3) rc -= 3;
  }
  // ---- tile 30 (rc == 0 here): consume bfE ----
  __builtin_amdgcn_s_barrier(); SBAR;
  LOAD_B(31, bfO); SBAR;
  COMPUTE(bfE, 0);
  SBAR;
  asm volatile("s_waitcnt vmcnt(8)" ::: "memory");   // certify sA(31)+lB(30)
  SBAR;
  // ---- tile 31 (slot 1): consume bfO ----
  __builtin_amdgcn_s_barrier(); SBAR;
  COMPUTE(bfO, 32768);

  // epilogue: C/D layout (m89-verified): col = lane&15, row = (lane>>4)*4+reg
  const float sc = params[2];
  const int crow = m0 + wm * 128 + q4 * 4;
  const int ccol = n0 + wn * 64 + r16;
#pragma unroll
  for (int i = 0; i < 8; ++i)
#pragma unroll
    for (int j = 0; j < 4; ++j)
#pragma unroll
      for (int r = 0; r < 4; ++r)
        C[(size_t)(crow + i * 16 + r) * N + (ccol + j * 16)] = (float)acc[i][j][r] * sc;
}

// ---------------- launch ----------------

extern "C" void kernel_launch(void* const* d_in, const int* in_sizes, int n_in,
                              void* d_out, int out_size, void* d_ws, size_t ws_size,
                              hipStream_t stream) {
  const float* x = (const float*)d_in[0];
  const float* w = (const float*)d_in[1];
  float* out = (float*)d_out;
  char* ws = (char*)d_ws;

  unsigned* gamma_bits = (unsigned*)ws;            // 4 B
  float*    params     = (float*)(ws + 16);        // 3 floats
  float*    partials   = (float*)(ws + 256);       // 2048 floats
  char*     xq  = ws + 16384;                      // 33,554,432 B (linear)
  char*     wq2 = ws + 16384 + (size_t)NX;         // 67,108,864 B (fragment layout)

  hipMemsetAsync(ws, 0, 256, stream);  // zero gamma accumulator each call

  reduce_absmax_kernel<<<NPART, 256, 0, stream>>>(x, gamma_bits, (int)(NX / 4));
  reduce_abssum_kernel<<<NPART, 256, 0, stream>>>(w, partials, (int)(NW / 4));
  finalize_kernel<<<1, 256, 0, stream>>>(gamma_bits, partials, params);
  quant_x_kernel<<<2048, 256, 0, stream>>>(x, xq, params, (int)(NX / 16));
  quant_w_kernel<<<4096, 256, 0, stream>>>(w, wq2, params, (int)(NW / 16));

  gemm_kernel<<<2048, 512, 0, stream>>>(xq, wq2, out, params);
}

// Round 9
// 765.054 us; speedup vs baseline: 1.0505x; 1.0505x over previous
//
#include <hip/hip_runtime.h>

typedef float f32x4  __attribute__((ext_vector_type(4)));
typedef int   i32x4  __attribute__((ext_vector_type(4)));
typedef int   i32x16 __attribute__((ext_vector_type(16)));
typedef char  s8x16  __attribute__((ext_vector_type(16)));

#define GAS __attribute__((address_space(1)))
#define LAS __attribute__((address_space(3)))
#define SBAR __builtin_amdgcn_sched_barrier(0)

constexpr int M = 8192;       // B*S
constexpr int N = 16384;      // D_OUT
constexpr int K = 4096;       // D_IN
constexpr long long NX = (long long)M * K;   // 33,554,432
constexpr long long NW = (long long)N * K;   // 67,108,864
constexpr int NPART = 2048;

constexpr int BKB    = 64;               // K-bytes per tile (i8)
constexpr int NTT    = K / BKB;          // 64 K-tiles
constexpr int ABYTES = 256 * BKB;        // 16384
constexpr int BBYTES = 128 * BKB;        // 8192
constexpr int BUFB   = ABYTES + BBYTES;  // 24576

// ---------------- reductions ----------------

__global__ void reduce_absmax_kernel(const float* __restrict__ x,
                                     unsigned* __restrict__ gmax, int n4) {
  float m = 0.f;
  int stride = gridDim.x * blockDim.x;
  for (int i = blockIdx.x * blockDim.x + threadIdx.x; i < n4; i += stride) {
    f32x4 v = *(const f32x4*)(x + (size_t)i * 4);
    m = fmaxf(m, fmaxf(fmaxf(fabsf(v[0]), fabsf(v[1])),
                       fmaxf(fabsf(v[2]), fabsf(v[3]))));
  }
#pragma unroll
  for (int off = 32; off > 0; off >>= 1) m = fmaxf(m, __shfl_down(m, off));
  __shared__ float sm[4];
  int lane = threadIdx.x & 63, wid = threadIdx.x >> 6;
  if (lane == 0) sm[wid] = m;
  __syncthreads();
  if (threadIdx.x == 0) {
    m = fmaxf(fmaxf(sm[0], sm[1]), fmaxf(sm[2], sm[3]));
    atomicMax(gmax, __float_as_uint(m));  // |x| >= 0: bit-order == float-order
  }
}

__global__ void reduce_abssum_kernel(const float* __restrict__ w,
                                     float* __restrict__ partials, int n4) {
  float s = 0.f;
  int stride = gridDim.x * blockDim.x;
  for (int i = blockIdx.x * blockDim.x + threadIdx.x; i < n4; i += stride) {
    f32x4 v = *(const f32x4*)(w + (size_t)i * 4);
    s += fabsf(v[0]) + fabsf(v[1]) + fabsf(v[2]) + fabsf(v[3]);
  }
#pragma unroll
  for (int off = 32; off > 0; off >>= 1) s += __shfl_down(s, off);
  __shared__ float sm[4];
  int lane = threadIdx.x & 63, wid = threadIdx.x >> 6;
  if (lane == 0) sm[wid] = s;
  __syncthreads();
  if (threadIdx.x == 0) partials[blockIdx.x] = (sm[0] + sm[1]) + (sm[2] + sm[3]);
}

__global__ void finalize_kernel(const unsigned* __restrict__ gbits,
                                const float* __restrict__ partials,
                                float* __restrict__ params) {
  __shared__ double sd[256];
  double s = 0.0;
  for (int i = threadIdx.x; i < NPART; i += 256) s += (double)partials[i];
  sd[threadIdx.x] = s;
  __syncthreads();
  for (int h = 128; h > 0; h >>= 1) {
    if (threadIdx.x < h) sd[threadIdx.x] += sd[threadIdx.x + h];
    __syncthreads();
  }
  if (threadIdx.x == 0) {
    float beta  = fmaxf((float)(sd[0] / (double)NW), 1e-5f);
    float gamma = fmaxf(__uint_as_float(gbits[0]), 1e-5f);
    params[0] = 128.0f / gamma;          // activation scale (q/gamma)
    params[1] = beta;                    // weight divisor
    params[2] = beta * gamma / 128.0f;   // output rescale
  }
}

// ---------------- quantization (int8 outputs, linear layouts) ----------------

__global__ void quant_x_kernel(const float* __restrict__ x,
                               char* __restrict__ xq,
                               const float* __restrict__ params, int n16) {
  float s = params[0];
  int stride = gridDim.x * blockDim.x;
  for (int i = blockIdx.x * blockDim.x + threadIdx.x; i < n16; i += stride) {
    const f32x4* p = (const f32x4*)(x + (size_t)i * 16);
    s8x16 o;
#pragma unroll
    for (int v = 0; v < 4; ++v) {
      f32x4 t = p[v];
#pragma unroll
      for (int k = 0; k < 4; ++k) {
        float r = fminf(fmaxf(rintf(t[k] * s), -128.f), 127.f);
        o[v * 4 + k] = (char)(int)r;
      }
    }
    *(s8x16*)(xq + (size_t)i * 16) = o;
  }
}

__global__ void quant_w_kernel(const float* __restrict__ w,
                               char* __restrict__ wq,
                               const float* __restrict__ params, int n16) {
  float beta = params[1];
  int stride = gridDim.x * blockDim.x;
  for (int i = blockIdx.x * blockDim.x + threadIdx.x; i < n16; i += stride) {
    const f32x4* p = (const f32x4*)(w + (size_t)i * 16);
    s8x16 o;
#pragma unroll
    for (int v = 0; v < 4; ++v) {
      f32x4 t = p[v];
#pragma unroll
      for (int k = 0; k < 4; ++k) {
        // round_clip(|w|/beta, -1, 1): nonneg -> {0,1}; IEEE div matches ref rounding
        o[v * 4 + k] = (rintf(fabsf(t[k]) / beta) >= 1.0f) ? (char)1 : (char)0;
      }
    }
    *(s8x16*)(wq + (size_t)i * 16) = o;
  }
}

// ---------------- GEMM: 256x128 tile, 8 waves x 64x64, BK=64B, 3-buf ring
// Round-6 skeleton (proven race-free, 2 blocks/CU for cross-block overlap),
// MFMA shape switched to mfma_i32_32x32x32_i8 (4404 vs 3944 TOPS ubench,
// half the instruction count -> half the issue pressure per tile).
// Per wave: 2x2 frags of 32x32, acc = 4 x i32x16 = 64 regs (unchanged).
// A-operand layout (x2-K doubling rule, validated for 16x16x64):
//   row = lane&31, k = (lane>>5)*16 + byte,  frag k-step = ks*32.
// C/D (m74/m101): col = lane&31, row = (reg&3) + 8*(reg>>2) + 4*(lane>>5).
// Swizzle (unchanged storage): LDS[row][s] = global[row][s ^ ((row>>1)&3)];
// 32-row read granules per 8 rows = {0,4,1,5,2,6,3,7} -> conflict-free.

__global__ __launch_bounds__(512, 4) void gemm_kernel(
    const char* __restrict__ A,   // xq int8 [M][K]
    const char* __restrict__ B,   // wq int8 [N][K]
    float* __restrict__ C,        // [M][N] fp32
    const float* __restrict__ params) {
  __shared__ __align__(16) char lds[3 * BUFB];   // 72 KiB

  const int tid  = threadIdx.x;
  const int lane = tid & 63, wid = tid >> 6;
  const int wm = wid >> 1, wn = wid & 1;          // 4x2 waves, each 64x64
  const int l31 = lane & 31, h = lane >> 5;

  // T1: XCD swizzle; grid 4096 = 32 m-tiles x 128 n-tiles, m-major chunks.
  const int wg = (blockIdx.x & 7) * 512 + (blockIdx.x >> 3);
  const int m0 = (wg >> 7) * 256, n0 = (wg & 127) * 128;

  // ---- staging (identical to round 6, proven) ----
  const int csw = (((lane & 3) ^ ((lane >> 3) & 3))) * 16;
  const char* gA = A + (size_t)(m0 + wid * 32 + (lane >> 2)) * K + csw;
  const char* gB = B + (size_t)(n0 + wid * 16 + (lane >> 2)) * K + csw;
  const int dA = wid * 2048 + lane * 16;
  const int dB = ABYTES + wid * 1024 + lane * 16;

  auto stage = [&](int t, int bo) {
    char* L = lds + bo;
    const char* a = gA + t * BKB;
    __builtin_amdgcn_global_load_lds((const GAS void*)a,              (LAS void*)(L + dA),        16, 0, 0);
    __builtin_amdgcn_global_load_lds((const GAS void*)(a + 16 * K),   (LAS void*)(L + dA + 1024), 16, 0, 0);
    __builtin_amdgcn_global_load_lds((const GAS void*)(gB + t * BKB), (LAS void*)(L + dB),        16, 0, 0);
  };

  // ---- fragment read offsets ----
  // want global bytes [ks*32 + h*16, +16) of row -> LDS slot (2ks+h)^((row>>1)&3);
  // row = base32 + l31 so swz = (l31>>1)&3.
  const int rsw = (l31 >> 1) & 3;
  int aoff[2][2], boff[2][2];
#pragma unroll
  for (int fm = 0; fm < 2; ++fm)
#pragma unroll
    for (int ks = 0; ks < 2; ++ks)
      aoff[fm][ks] = (wm * 64 + fm * 32 + l31) * BKB + (((ks * 2 + h) ^ rsw) * 16);
#pragma unroll
  for (int fn = 0; fn < 2; ++fn)
#pragma unroll
    for (int ks = 0; ks < 2; ++ks)
      boff[fn][ks] = ABYTES + (wn * 64 + fn * 32 + l31) * BKB + (((ks * 2 + h) ^ rsw) * 16);

  i32x16 acc[2][2] = {};

  auto compute = [&](int bo) {
    const char* buf = lds + bo;
    i32x4 af[2][2], bf[2][2];
#pragma unroll
    for (int fm = 0; fm < 2; ++fm)
#pragma unroll
      for (int ks = 0; ks < 2; ++ks)
        af[fm][ks] = *(const i32x4*)(buf + aoff[fm][ks]);
#pragma unroll
    for (int fn = 0; fn < 2; ++fn)
#pragma unroll
      for (int ks = 0; ks < 2; ++ks)
        bf[fn][ks] = *(const i32x4*)(buf + boff[fn][ks]);
    __builtin_amdgcn_s_setprio(1);
#pragma unroll
    for (int fm = 0; fm < 2; ++fm)
#pragma unroll
      for (int fn = 0; fn < 2; ++fn)
#pragma unroll
        for (int ks = 0; ks < 2; ++ks)
          acc[fm][fn] = __builtin_amdgcn_mfma_i32_32x32x32_i8(af[fm][ks], bf[fn][ks], acc[fm][fn], 0, 0, 0);
    __builtin_amdgcn_s_setprio(0);
  };

  // prologue: tiles 0,1 in flight (6 vm ops)
  stage(0, 0);
  stage(1, BUFB);

  int cb = 0, sb = 2 * BUFB;
  for (int t = 0; t < NTT - 1; ++t) {
    // outstanding: tiles t, t+1 (6 ops); in-order retirement -> vmcnt(3)
    // certifies tile t resident (this wave's share).
    asm volatile("s_waitcnt vmcnt(3)" ::: "memory");
    SBAR;
    // barrier: all waves' tile-t shares resident AND all waves done reading
    // tile t-1 (ds_reads retired before their MFMAs which precede arrival),
    // so stage(t+2) overwriting buf[t-1] below is race-free.
    __builtin_amdgcn_s_barrier();
    SBAR;
    if (t + 2 < NTT) stage(t + 2, sb);
    compute(cb);
    cb = (cb == 2 * BUFB) ? 0 : cb + BUFB;
    sb = (sb == 2 * BUFB) ? 0 : sb + BUFB;
  }
  asm volatile("s_waitcnt vmcnt(0)" ::: "memory");
  SBAR;
  __builtin_amdgcn_s_barrier();
  SBAR;
  compute(cb);

  // epilogue: C/D 32x32 layout: col = lane&31, row = (reg&3)+8*(reg>>2)+4*h
  const float sc = params[2];
#pragma unroll
  for (int fm = 0; fm < 2; ++fm)
#pragma unroll
    for (int fn = 0; fn < 2; ++fn) {
      const int crow = m0 + wm * 64 + fm * 32 + h * 4;
      const int ccol = n0 + wn * 64 + fn * 32 + l31;
#pragma unroll
      for (int r = 0; r < 16; ++r) {
        const int row = crow + (r & 3) + 8 * (r >> 2);
        C[(size_t)row * N + ccol] = (float)acc[fm][fn][r] * sc;
      }
    }
}

// ---------------- launch ----------------

extern "C" void kernel_launch(void* const* d_in, const int* in_sizes, int n_in,
                              void* d_out, int out_size, void* d_ws, size_t ws_size,
                              hipStream_t stream) {
  const float* x = (const float*)d_in[0];
  const float* w = (const float*)d_in[1];
  float* out = (float*)d_out;
  char* ws = (char*)d_ws;

  unsigned* gamma_bits = (unsigned*)ws;            // 4 B
  float*    params     = (float*)(ws + 16);        // 3 floats
  float*    partials   = (float*)(ws + 256);       // 2048 floats
  char*     xq = ws + 16384;                       // 33,554,432 B
  char*     wq = ws + 16384 + (size_t)NX;          // 67,108,864 B

  hipMemsetAsync(ws, 0, 256, stream);  // zero gamma accumulator each call

  reduce_absmax_kernel<<<NPART, 256, 0, stream>>>(x, gamma_bits, (int)(NX / 4));
  reduce_abssum_kernel<<<NPART, 256, 0, stream>>>(w, partials, (int)(NW / 4));
  finalize_kernel<<<1, 256, 0, stream>>>(gamma_bits, partials, params);
  quant_x_kernel<<<2048, 256, 0, stream>>>(x, xq, params, (int)(NX / 16));
  quant_w_kernel<<<2048, 256, 0, stream>>>(w, wq, params, (int)(NW / 16));

  gemm_kernel<<<4096, 512, 0, stream>>>(xq, wq, out, params);
}